// Round 1
// baseline (163.170 us; speedup 1.0000x reference)
//
#include <hip/hip_runtime.h>
#include <hip/hip_bf16.h>
#include <cstdint>
#include <cstddef>

// ---------------------------------------------------------------------------
// Mamba block forward, MI355X (gfx950).
// Shapes: B=1, L=1024, D_MODEL=1024, D_INNER=2048, D_STATE=16, DT_RANK=64,
//         D_CONV=4.
// Pipeline:
//   1. convert_all : fp32 -> bf16 copies of x and the 4 matmul weights
//   2. gemm_bt_128 : xz = x @ in_proj_w^T            [1024 x 4096] fp32
//   3. conv_silu   : causal depthwise conv + silu -> xi (fp32 + bf16)
//   4. xproj       : x_dbl = xi @ x_proj_w^T -> delta_raw(bf16), Bm, Cm (fp32)
//   5. dtproj      : delta = softplus(delta_raw @ dt_proj_w^T + b)  fp32
//   6. scan_p1/p2/p3 : chunked linear scan (32 chunks x 32 steps),
//                      p3 fuses y = (sum_n s*C) + u*D, y *= silu(z), cast bf16
//   7. gemm_bt_128 : out = y @ out_proj_w^T          [1024 x 1024] fp32
// Precision: bf16 inputs / fp32 accum for all GEMMs; scan fully fp32.
// Threshold is 2% of max|ref| -> bf16 GEMM error (~0.5% rel) is safe.
// ---------------------------------------------------------------------------

typedef __attribute__((ext_vector_type(4))) float f32x4;
typedef __attribute__((ext_vector_type(8))) short short8;

__device__ __forceinline__ unsigned short f2bf(float f) {
  union { float f; unsigned u; } v; v.f = f;
  unsigned u = v.u;
  unsigned r = (u + 0x7FFFu + ((u >> 16) & 1u)) >> 16;  // round-to-nearest-even
  return (unsigned short)r;
}

// ---------------------------------------------------------------------------
// fp32 -> bf16 conversion for 5 arrays (blockIdx.y picks the array)
// ---------------------------------------------------------------------------
__global__ __launch_bounds__(256) void convert_all(
    const float* __restrict__ a0, unsigned short* __restrict__ o0, int n0,
    const float* __restrict__ a1, unsigned short* __restrict__ o1, int n1,
    const float* __restrict__ a2, unsigned short* __restrict__ o2, int n2,
    const float* __restrict__ a3, unsigned short* __restrict__ o3, int n3,
    const float* __restrict__ a4, unsigned short* __restrict__ o4, int n4) {
  const float* a; unsigned short* o; int n;
  switch (blockIdx.y) {
    case 0: a = a0; o = o0; n = n0; break;
    case 1: a = a1; o = o1; n = n1; break;
    case 2: a = a2; o = o2; n = n2; break;
    case 3: a = a3; o = o3; n = n3; break;
    default: a = a4; o = o4; n = n4; break;
  }
  int n4c = n >> 2;
  int stride = gridDim.x * blockDim.x;
  for (int i = blockIdx.x * blockDim.x + threadIdx.x; i < n4c; i += stride) {
    float4 v = ((const float4*)a)[i];
    uint2 p;
    p.x = (unsigned)f2bf(v.x) | ((unsigned)f2bf(v.y) << 16);
    p.y = (unsigned)f2bf(v.z) | ((unsigned)f2bf(v.w) << 16);
    ((uint2*)o)[i] = p;
  }
}

// ---------------------------------------------------------------------------
// 128x128-tile bf16 GEMM, C = A @ B^T (both operands row-major over K).
// 256 threads = 4 waves in 2x2; each wave owns a 64x64 sub-tile = 4x4 frags
// of mfma_f32_16x16x32_bf16. BK=32. Reg-staged LDS (round-1 safe path).
// Requires M%128==0, N%128==0, K%32==0.
// ---------------------------------------------------------------------------
__global__ __launch_bounds__(256) void gemm_bt_128(
    const unsigned short* __restrict__ A, const unsigned short* __restrict__ B,
    float* __restrict__ C, int M, int N, int K) {
  __shared__ unsigned short lA[128 * 32];
  __shared__ unsigned short lB[128 * 32];
  const int tid  = threadIdx.x;
  const int lane = tid & 63;
  const int w    = tid >> 6;
  const int mBase = blockIdx.y * 128;
  const int nBase = blockIdx.x * 128;
  const int wr = (w >> 1) * 64;   // wave row offset in tile
  const int wc = (w & 1) * 64;    // wave col offset in tile

  f32x4 acc[4][4];
  #pragma unroll
  for (int m = 0; m < 4; ++m)
    #pragma unroll
    for (int n = 0; n < 4; ++n)
      acc[m][n] = (f32x4){0.f, 0.f, 0.f, 0.f};

  for (int k0 = 0; k0 < K; k0 += 32) {
    // stage 128x32 bf16 tiles of A and B: 512 16-byte chunks each,
    // 2 per thread, coalesced (4 threads cover one 64B row-slab).
    #pragma unroll
    for (int j = 0; j < 2; ++j) {
      int chunk = tid + j * 256;
      int row = chunk >> 2, c8 = chunk & 3;
      *(int4*)&lA[chunk * 8] =
          *(const int4*)&A[(size_t)(mBase + row) * K + k0 + c8 * 8];
      *(int4*)&lB[chunk * 8] =
          *(const int4*)&B[(size_t)(nBase + row) * K + k0 + c8 * 8];
    }
    __syncthreads();
    short8 af[4], bf[4];
    #pragma unroll
    for (int m = 0; m < 4; ++m)
      af[m] = *(const short8*)&lA[(wr + m * 16 + (lane & 15)) * 32 + (lane >> 4) * 8];
    #pragma unroll
    for (int n = 0; n < 4; ++n)
      bf[n] = *(const short8*)&lB[(wc + n * 16 + (lane & 15)) * 32 + (lane >> 4) * 8];
    #pragma unroll
    for (int m = 0; m < 4; ++m)
      #pragma unroll
      for (int n = 0; n < 4; ++n)
        acc[m][n] = __builtin_amdgcn_mfma_f32_16x16x32_bf16(af[m], bf[n], acc[m][n], 0, 0, 0);
    __syncthreads();
  }

  // C/D layout (m89-verified): col = lane&15, row = (lane>>4)*4 + reg
  #pragma unroll
  for (int m = 0; m < 4; ++m) {
    int row0 = mBase + wr + m * 16 + (lane >> 4) * 4;
    #pragma unroll
    for (int n = 0; n < 4; ++n) {
      int col = nBase + wc + n * 16 + (lane & 15);
      #pragma unroll
      for (int r = 0; r < 4; ++r)
        C[(size_t)(row0 + r) * N + col] = acc[m][n][r];
    }
  }
}

// ---------------------------------------------------------------------------
// causal depthwise conv (width 4) + silu; writes xi in fp32 and bf16
// grid (2048/256, 1024)
// ---------------------------------------------------------------------------
__global__ __launch_bounds__(256) void conv_silu(
    const float* __restrict__ xz, const float* __restrict__ cw,
    const float* __restrict__ cb, float* __restrict__ xi_f,
    unsigned short* __restrict__ xi_b) {
  int d = blockIdx.x * 256 + threadIdx.x;  // 0..2047
  int l = blockIdx.y;                      // 0..1023
  float acc = cb[d];
  #pragma unroll
  for (int k = 0; k < 4; ++k) {
    int ll = l - 3 + k;
    if (ll >= 0) acc += xz[(size_t)ll * 4096 + d] * cw[d * 4 + k];
  }
  float s = acc / (1.f + __expf(-acc));  // silu
  xi_f[(size_t)l * 2048 + d] = s;
  xi_b[(size_t)l * 2048 + d] = f2bf(s);
}

// ---------------------------------------------------------------------------
// x_dbl = xi @ x_proj_w^T  (M=1024, N=96, K=2048), one wave per 16x16 tile.
// cols 0..63 -> delta_raw (bf16), 64..79 -> Bm (fp32), 80..95 -> Cm (fp32)
// ---------------------------------------------------------------------------
__global__ __launch_bounds__(64) void xproj(
    const unsigned short* __restrict__ xi_b, const unsigned short* __restrict__ xw_b,
    unsigned short* __restrict__ xd_b, float* __restrict__ Bm, float* __restrict__ Cm) {
  int lane = threadIdx.x;
  int mt = blockIdx.x, nt = blockIdx.y;
  int arow = mt * 16 + (lane & 15);
  int brow = nt * 16 + (lane & 15);
  int kg = (lane >> 4) * 8;
  f32x4 acc = (f32x4){0.f, 0.f, 0.f, 0.f};
  for (int k0 = 0; k0 < 2048; k0 += 32) {
    short8 a = *(const short8*)&xi_b[(size_t)arow * 2048 + k0 + kg];
    short8 b = *(const short8*)&xw_b[(size_t)brow * 2048 + k0 + kg];
    acc = __builtin_amdgcn_mfma_f32_16x16x32_bf16(a, b, acc, 0, 0, 0);
  }
  int ocol = nt * 16 + (lane & 15);
  #pragma unroll
  for (int r = 0; r < 4; ++r) {
    int row = mt * 16 + (lane >> 4) * 4 + r;
    float v = acc[r];
    if (ocol < 64)      xd_b[row * 64 + ocol] = f2bf(v);
    else if (ocol < 80) Bm[row * 16 + (ocol - 64)] = v;
    else                Cm[row * 16 + (ocol - 80)] = v;
  }
}

// ---------------------------------------------------------------------------
// delta = softplus(delta_raw @ dt_proj_w^T + dt_proj_b)  (M=1024,N=2048,K=64)
// ---------------------------------------------------------------------------
__global__ __launch_bounds__(64) void dtproj(
    const unsigned short* __restrict__ xd_b, const unsigned short* __restrict__ dtw_b,
    const float* __restrict__ dtb, float* __restrict__ delta) {
  int lane = threadIdx.x;
  int mt = blockIdx.x, nt = blockIdx.y;
  int arow = mt * 16 + (lane & 15);
  int brow = nt * 16 + (lane & 15);
  int kg = (lane >> 4) * 8;
  f32x4 acc = (f32x4){0.f, 0.f, 0.f, 0.f};
  #pragma unroll
  for (int k0 = 0; k0 < 64; k0 += 32) {
    short8 a = *(const short8*)&xd_b[arow * 64 + k0 + kg];
    short8 b = *(const short8*)&dtw_b[brow * 64 + k0 + kg];
    acc = __builtin_amdgcn_mfma_f32_16x16x32_bf16(a, b, acc, 0, 0, 0);
  }
  int ocol = nt * 16 + (lane & 15);
  float bias = dtb[ocol];
  #pragma unroll
  for (int r = 0; r < 4; ++r) {
    int row = mt * 16 + (lane >> 4) * 4 + r;
    float v = acc[r] + bias;
    float sp = (v > 20.f) ? v : log1pf(__expf(v));  // softplus
    delta[(size_t)row * 2048 + ocol] = sp;
  }
}

// ---------------------------------------------------------------------------
// Chunked selective scan. 32 chunks of 32 timesteps. Lane owns channel d,
// 16 states in registers. P/S/SIn layout: [c][n][d] (coalesced over d).
// ---------------------------------------------------------------------------
__global__ __launch_bounds__(64) void scan_p1(
    const float* __restrict__ delta, const float* __restrict__ xi_f,
    const float* __restrict__ Bm, const float* __restrict__ A_log,
    float* __restrict__ P, float* __restrict__ S) {
  int d = blockIdx.x * 64 + threadIdx.x;
  int c = blockIdx.y;
  float a[16], p[16], s[16];
  #pragma unroll
  for (int n = 0; n < 16; ++n) {
    a[n] = -__expf(A_log[d * 16 + n]);
    p[n] = 1.f; s[n] = 0.f;
  }
  for (int t = 0; t < 32; ++t) {
    int l = c * 32 + t;
    float dl = delta[(size_t)l * 2048 + d];
    float u  = xi_f[(size_t)l * 2048 + d];
    float du = dl * u;
    float bv[16];
    *(float4*)(bv + 0)  = *(const float4*)&Bm[l * 16 + 0];
    *(float4*)(bv + 4)  = *(const float4*)&Bm[l * 16 + 4];
    *(float4*)(bv + 8)  = *(const float4*)&Bm[l * 16 + 8];
    *(float4*)(bv + 12) = *(const float4*)&Bm[l * 16 + 12];
    #pragma unroll
    for (int n = 0; n < 16; ++n) {
      float dA = __expf(dl * a[n]);
      s[n] = fmaf(dA, s[n], du * bv[n]);
      p[n] *= dA;
    }
  }
  #pragma unroll
  for (int n = 0; n < 16; ++n) {
    P[(size_t)(c * 16 + n) * 2048 + d] = p[n];
    S[(size_t)(c * 16 + n) * 2048 + d] = s[n];
  }
}

__global__ __launch_bounds__(256) void scan_p2(
    const float* __restrict__ P, const float* __restrict__ S,
    float* __restrict__ SIn) {
  int idx = blockIdx.x * 256 + threadIdx.x;  // 0..32767 = n*2048+d
  float sin_ = 0.f;
  for (int c = 0; c < 32; ++c) {
    SIn[c * 32768 + idx] = sin_;
    sin_ = fmaf(P[c * 32768 + idx], sin_, S[c * 32768 + idx]);
  }
}

__global__ __launch_bounds__(64) void scan_p3(
    const float* __restrict__ delta, const float* __restrict__ xi_f,
    const float* __restrict__ Bm, const float* __restrict__ Cm,
    const float* __restrict__ A_log, const float* __restrict__ Dv,
    const float* __restrict__ SIn, const float* __restrict__ xz,
    unsigned short* __restrict__ y_b) {
  int d = blockIdx.x * 64 + threadIdx.x;
  int c = blockIdx.y;
  float a[16], s[16];
  #pragma unroll
  for (int n = 0; n < 16; ++n) {
    a[n] = -__expf(A_log[d * 16 + n]);
    s[n] = SIn[c * 32768 + n * 2048 + d];
  }
  float Dd = Dv[d];
  for (int t = 0; t < 32; ++t) {
    int l = c * 32 + t;
    float dl = delta[(size_t)l * 2048 + d];
    float u  = xi_f[(size_t)l * 2048 + d];
    float du = dl * u;
    float bv[16], cv[16];
    *(float4*)(bv + 0)  = *(const float4*)&Bm[l * 16 + 0];
    *(float4*)(bv + 4)  = *(const float4*)&Bm[l * 16 + 4];
    *(float4*)(bv + 8)  = *(const float4*)&Bm[l * 16 + 8];
    *(float4*)(bv + 12) = *(const float4*)&Bm[l * 16 + 12];
    *(float4*)(cv + 0)  = *(const float4*)&Cm[l * 16 + 0];
    *(float4*)(cv + 4)  = *(const float4*)&Cm[l * 16 + 4];
    *(float4*)(cv + 8)  = *(const float4*)&Cm[l * 16 + 8];
    *(float4*)(cv + 12) = *(const float4*)&Cm[l * 16 + 12];
    float y = 0.f;
    #pragma unroll
    for (int n = 0; n < 16; ++n) {
      float dA = __expf(dl * a[n]);
      s[n] = fmaf(dA, s[n], du * bv[n]);
      y = fmaf(s[n], cv[n], y);
    }
    y = fmaf(u, Dd, y);
    float zz = xz[(size_t)l * 4096 + 2048 + d];
    float sig = 1.f / (1.f + __expf(-zz));
    y *= zz * sig;  // y * silu(z)
    y_b[(size_t)l * 2048 + d] = f2bf(y);
  }
}

// ---------------------------------------------------------------------------
extern "C" void kernel_launch(void* const* d_in, const int* in_sizes, int n_in,
                              void* d_out, int out_size, void* d_ws, size_t ws_size,
                              hipStream_t stream) {
  const float* x      = (const float*)d_in[0];
  const float* Win    = (const float*)d_in[1];
  const float* convw  = (const float*)d_in[2];
  const float* convb  = (const float*)d_in[3];
  const float* xprojw = (const float*)d_in[4];
  const float* dtw    = (const float*)d_in[5];
  const float* dtb    = (const float*)d_in[6];
  const float* Alog   = (const float*)d_in[7];
  const float* Dv     = (const float*)d_in[8];
  const float* Wout   = (const float*)d_in[9];
  float* out = (float*)d_out;

  char* ws = (char*)d_ws;
  size_t off = 0;
  auto alloc = [&](size_t bytes) -> void* {
    void* p = ws + off;
    off = (off + bytes + 255) & ~(size_t)255;
    return p;
  };
  unsigned short* x_bf    = (unsigned short*)alloc((size_t)1024 * 1024 * 2);
  unsigned short* Win_bf  = (unsigned short*)alloc((size_t)4096 * 1024 * 2);
  unsigned short* Wout_bf = (unsigned short*)alloc((size_t)1024 * 2048 * 2);
  unsigned short* xw_bf   = (unsigned short*)alloc((size_t)96 * 2048 * 2);
  unsigned short* dtw_bf  = (unsigned short*)alloc((size_t)2048 * 64 * 2);
  float* xz               = (float*)alloc((size_t)1024 * 4096 * 4);
  float* xi_f             = (float*)alloc((size_t)1024 * 2048 * 4);
  unsigned short* xi_bf   = (unsigned short*)alloc((size_t)1024 * 2048 * 2);
  unsigned short* xd_bf   = (unsigned short*)alloc((size_t)1024 * 64 * 2);
  float* Bm               = (float*)alloc((size_t)1024 * 16 * 4);
  float* Cm               = (float*)alloc((size_t)1024 * 16 * 4);
  float* delta            = (float*)alloc((size_t)1024 * 2048 * 4);
  float* P                = (float*)alloc((size_t)32 * 16 * 2048 * 4);
  float* S                = (float*)alloc((size_t)32 * 16 * 2048 * 4);
  float* SIn              = (float*)alloc((size_t)32 * 16 * 2048 * 4);
  unsigned short* y_bf    = (unsigned short*)alloc((size_t)1024 * 2048 * 2);
  // total ~67 MB of d_ws

  convert_all<<<dim3(512, 5), 256, 0, stream>>>(
      x, x_bf, 1024 * 1024,
      Win, Win_bf, 4096 * 1024,
      Wout, Wout_bf, 1024 * 2048,
      xprojw, xw_bf, 96 * 2048,
      dtw, dtw_bf, 2048 * 64);
  gemm_bt_128<<<dim3(32, 8), 256, 0, stream>>>(x_bf, Win_bf, xz, 1024, 4096, 1024);
  conv_silu<<<dim3(8, 1024), 256, 0, stream>>>(xz, convw, convb, xi_f, xi_bf);
  xproj<<<dim3(64, 6), 64, 0, stream>>>(xi_bf, xw_bf, xd_bf, Bm, Cm);
  dtproj<<<dim3(64, 128), 64, 0, stream>>>(xd_bf, dtw_bf, dtb, delta);
  scan_p1<<<dim3(32, 32), 64, 0, stream>>>(delta, xi_f, Bm, Alog, P, S);
  scan_p2<<<dim3(128), 256, 0, stream>>>(P, S, SIn);
  scan_p3<<<dim3(32, 32), 64, 0, stream>>>(delta, xi_f, Bm, Cm, Alog, Dv, SIn, xz, y_bf);
  gemm_bt_128<<<dim3(8, 8), 256, 0, stream>>>(y_bf, Wout_bf, out, 1024, 1024, 2048);
}

// Round 2
// 117.947 us; speedup vs baseline: 1.3834x; 1.3834x over previous
//
#include <hip/hip_runtime.h>
#include <hip/hip_bf16.h>
#include <cstdint>
#include <cstddef>

// ---------------------------------------------------------------------------
// Mamba block forward, MI355X (gfx950).  Round 2.
// Changes vs round 1:
//  - gemm64: 64x64 tile / BK=64 / 4 waves / double-buffered LDS /
//    global_load_lds(16B) staging with XOR k-slot swizzle (both sides).
//    in_proj: 1024 blocks (4/CU).  out_proj: split-K=2 (512 blocks) +
//    reduce2, partials reuse dead P/S scan buffers.
//  - xproj: 4-wave K-split + LDS reduction (was 1 serial wave over K=2048).
// ---------------------------------------------------------------------------

typedef __attribute__((ext_vector_type(4))) float f32x4;
typedef __attribute__((ext_vector_type(8))) short short8;

#define GLOAD_LDS16(g, l)                                                      \
  __builtin_amdgcn_global_load_lds(                                            \
      (const __attribute__((address_space(1))) void*)(g),                      \
      (__attribute__((address_space(3))) void*)(l), 16, 0, 0)

__device__ __forceinline__ unsigned short f2bf(float f) {
  union { float f; unsigned u; } v; v.f = f;
  unsigned u = v.u;
  unsigned r = (u + 0x7FFFu + ((u >> 16) & 1u)) >> 16;  // round-to-nearest-even
  return (unsigned short)r;
}

// ---------------------------------------------------------------------------
// fp32 -> bf16 conversion for 5 arrays (blockIdx.y picks the array)
// ---------------------------------------------------------------------------
__global__ __launch_bounds__(256) void convert_all(
    const float* __restrict__ a0, unsigned short* __restrict__ o0, int n0,
    const float* __restrict__ a1, unsigned short* __restrict__ o1, int n1,
    const float* __restrict__ a2, unsigned short* __restrict__ o2, int n2,
    const float* __restrict__ a3, unsigned short* __restrict__ o3, int n3,
    const float* __restrict__ a4, unsigned short* __restrict__ o4, int n4) {
  const float* a; unsigned short* o; int n;
  switch (blockIdx.y) {
    case 0: a = a0; o = o0; n = n0; break;
    case 1: a = a1; o = o1; n = n1; break;
    case 2: a = a2; o = o2; n = n2; break;
    case 3: a = a3; o = o3; n = n3; break;
    default: a = a4; o = o4; n = n4; break;
  }
  int n4c = n >> 2;
  int stride = gridDim.x * blockDim.x;
  for (int i = blockIdx.x * blockDim.x + threadIdx.x; i < n4c; i += stride) {
    float4 v = ((const float4*)a)[i];
    uint2 p;
    p.x = (unsigned)f2bf(v.x) | ((unsigned)f2bf(v.y) << 16);
    p.y = (unsigned)f2bf(v.z) | ((unsigned)f2bf(v.w) << 16);
    ((uint2*)o)[i] = p;
  }
}

// ---------------------------------------------------------------------------
// 64x64-tile bf16 GEMM, C = A @ B^T.  4 waves, each owns 32x32 (2x2 frags of
// mfma_f32_16x16x32_bf16, 2 k-steps per BK=64 iter).  Double-buffered LDS,
// global_load_lds 16B staging.  XOR swizzle on 16B k-slots: phys = s^(row&7),
// applied on the GLOBAL source (inverse) and the ds_read (forward) — LDS
// destination stays linear (global_load_lds requirement).
// Requires M%64==0, N%64==0, (K/SPLITK)%64==0.
// ---------------------------------------------------------------------------
template <int SPLITK>
__global__ __launch_bounds__(256) void gemm64(
    const unsigned short* __restrict__ A, const unsigned short* __restrict__ B,
    float* __restrict__ C, int M, int N, int K) {
  __shared__ unsigned short lds[2][2][64 * 64];  // [buf][A/B][row*64+col] 32KB
  const int tid  = threadIdx.x;
  const int lane = tid & 63;
  const int w    = tid >> 6;
  const int mBase = blockIdx.y * 64;
  const int nBase = blockIdx.x * 64;
  const int kLen  = K / SPLITK;
  const int kBase = (SPLITK > 1) ? blockIdx.z * kLen : 0;
  const int wr = (w >> 1) * 32;
  const int wc = (w & 1) * 32;
  const int wchunk = tid & 192;  // wave base chunk (64*w)

  f32x4 acc[2][2];
  #pragma unroll
  for (int m = 0; m < 2; ++m)
    #pragma unroll
    for (int n = 0; n < 2; ++n)
      acc[m][n] = (f32x4){0.f, 0.f, 0.f, 0.f};

  auto stage = [&](int b, int k0) {
    #pragma unroll
    for (int j = 0; j < 2; ++j) {
      int chunk = tid + j * 256;       // 0..511 : 16B chunks of the 8KB tile
      int row = chunk >> 3;            // 8 chunks per 128B row
      int t = chunk & 7;               // physical 16B slot in row
      int col = (t ^ (row & 7)) * 8;   // logical element offset (inverse swz)
      GLOAD_LDS16(&A[(size_t)(mBase + row) * K + k0 + col],
                  &lds[b][0][(size_t)(wchunk + j * 256) * 8]);
      GLOAD_LDS16(&B[(size_t)(nBase + row) * K + k0 + col],
                  &lds[b][1][(size_t)(wchunk + j * 256) * 8]);
    }
  };

  const int kIters = kLen / 64;
  stage(0, kBase);
  __syncthreads();  // drains vmcnt(0)
  int buf = 0;
  for (int it = 0; it < kIters; ++it) {
    if (it + 1 < kIters) stage(buf ^ 1, kBase + (it + 1) * 64);
    short8 af[2][2], bfr[2][2];
    #pragma unroll
    for (int m = 0; m < 2; ++m)
      #pragma unroll
      for (int kk = 0; kk < 2; ++kk) {
        int row = wr + m * 16 + (lane & 15);
        int s = kk * 4 + (lane >> 4);
        af[m][kk] = *(const short8*)&lds[buf][0][row * 64 + ((s ^ (row & 7)) * 8)];
      }
    #pragma unroll
    for (int n = 0; n < 2; ++n)
      #pragma unroll
      for (int kk = 0; kk < 2; ++kk) {
        int row = wc + n * 16 + (lane & 15);
        int s = kk * 4 + (lane >> 4);
        bfr[n][kk] = *(const short8*)&lds[buf][1][row * 64 + ((s ^ (row & 7)) * 8)];
      }
    #pragma unroll
    for (int kk = 0; kk < 2; ++kk)
      #pragma unroll
      for (int m = 0; m < 2; ++m)
        #pragma unroll
        for (int n = 0; n < 2; ++n)
          acc[m][n] = __builtin_amdgcn_mfma_f32_16x16x32_bf16(
              af[m][kk], bfr[n][kk], acc[m][n], 0, 0, 0);
    __syncthreads();  // drains vmcnt(0): prefetch landed; buf reads done
    buf ^= 1;
  }

  float* Co = C + (SPLITK > 1 ? (size_t)blockIdx.z * M * N : (size_t)0);
  #pragma unroll
  for (int m = 0; m < 2; ++m) {
    int row0 = mBase + wr + m * 16 + (lane >> 4) * 4;
    #pragma unroll
    for (int n = 0; n < 2; ++n) {
      int col = nBase + wc + n * 16 + (lane & 15);
      #pragma unroll
      for (int r = 0; r < 4; ++r)
        Co[(size_t)(row0 + r) * N + col] = acc[m][n][r];
    }
  }
}

// out = partial0 + partial1 (split-K reduce), vectorized
__global__ __launch_bounds__(256) void reduce2(
    const float* __restrict__ P, float* __restrict__ out, int n4) {
  int i = blockIdx.x * 256 + threadIdx.x;
  if (i < n4) {
    f32x4 a = ((const f32x4*)P)[i];
    f32x4 b = ((const f32x4*)P)[i + n4];
    ((f32x4*)out)[i] = a + b;
  }
}

// ---------------------------------------------------------------------------
// causal depthwise conv (width 4) + silu; writes xi in fp32 and bf16
// ---------------------------------------------------------------------------
__global__ __launch_bounds__(256) void conv_silu(
    const float* __restrict__ xz, const float* __restrict__ cw,
    const float* __restrict__ cb, float* __restrict__ xi_f,
    unsigned short* __restrict__ xi_b) {
  int d = blockIdx.x * 256 + threadIdx.x;  // 0..2047
  int l = blockIdx.y;                      // 0..1023
  float acc = cb[d];
  #pragma unroll
  for (int k = 0; k < 4; ++k) {
    int ll = l - 3 + k;
    if (ll >= 0) acc += xz[(size_t)ll * 4096 + d] * cw[d * 4 + k];
  }
  float s = acc / (1.f + __expf(-acc));  // silu
  xi_f[(size_t)l * 2048 + d] = s;
  xi_b[(size_t)l * 2048 + d] = f2bf(s);
}

// ---------------------------------------------------------------------------
// x_dbl = xi @ x_proj_w^T  (M=1024, N=96, K=2048).  4 waves split K, LDS
// reduce, wave 0 writes.  cols 0..63 -> delta_raw (bf16), 64..79 -> Bm,
// 80..95 -> Cm (fp32)
// ---------------------------------------------------------------------------
__global__ __launch_bounds__(256) void xproj(
    const unsigned short* __restrict__ xi_b, const unsigned short* __restrict__ xw_b,
    unsigned short* __restrict__ xd_b, float* __restrict__ Bm, float* __restrict__ Cm) {
  __shared__ f32x4 red[4][64];
  int tid = threadIdx.x, lane = tid & 63, w = tid >> 6;
  int mt = blockIdx.x, nt = blockIdx.y;
  int arow = mt * 16 + (lane & 15);
  int brow = nt * 16 + (lane & 15);
  int kg = (lane >> 4) * 8;
  f32x4 acc = (f32x4){0.f, 0.f, 0.f, 0.f};
  for (int k0 = w * 512; k0 < (w + 1) * 512; k0 += 32) {
    short8 a = *(const short8*)&xi_b[(size_t)arow * 2048 + k0 + kg];
    short8 b = *(const short8*)&xw_b[(size_t)brow * 2048 + k0 + kg];
    acc = __builtin_amdgcn_mfma_f32_16x16x32_bf16(a, b, acc, 0, 0, 0);
  }
  red[w][lane] = acc;
  __syncthreads();
  if (w == 0) {
    acc = red[0][lane];
    acc += red[1][lane];
    acc += red[2][lane];
    acc += red[3][lane];
    int ocol = nt * 16 + (lane & 15);
    #pragma unroll
    for (int r = 0; r < 4; ++r) {
      int row = mt * 16 + (lane >> 4) * 4 + r;
      float v = acc[r];
      if (ocol < 64)      xd_b[row * 64 + ocol] = f2bf(v);
      else if (ocol < 80) Bm[row * 16 + (ocol - 64)] = v;
      else                Cm[row * 16 + (ocol - 80)] = v;
    }
  }
}

// ---------------------------------------------------------------------------
// delta = softplus(delta_raw @ dt_proj_w^T + dt_proj_b)  (M=1024,N=2048,K=64)
// ---------------------------------------------------------------------------
__global__ __launch_bounds__(64) void dtproj(
    const unsigned short* __restrict__ xd_b, const unsigned short* __restrict__ dtw_b,
    const float* __restrict__ dtb, float* __restrict__ delta) {
  int lane = threadIdx.x;
  int mt = blockIdx.x, nt = blockIdx.y;
  int arow = mt * 16 + (lane & 15);
  int brow = nt * 16 + (lane & 15);
  int kg = (lane >> 4) * 8;
  f32x4 acc = (f32x4){0.f, 0.f, 0.f, 0.f};
  #pragma unroll
  for (int k0 = 0; k0 < 64; k0 += 32) {
    short8 a = *(const short8*)&xd_b[arow * 64 + k0 + kg];
    short8 b = *(const short8*)&dtw_b[brow * 64 + k0 + kg];
    acc = __builtin_amdgcn_mfma_f32_16x16x32_bf16(a, b, acc, 0, 0, 0);
  }
  int ocol = nt * 16 + (lane & 15);
  float bias = dtb[ocol];
  #pragma unroll
  for (int r = 0; r < 4; ++r) {
    int row = mt * 16 + (lane >> 4) * 4 + r;
    float v = acc[r] + bias;
    float sp = (v > 20.f) ? v : log1pf(__expf(v));  // softplus
    delta[(size_t)row * 2048 + ocol] = sp;
  }
}

// ---------------------------------------------------------------------------
// Chunked selective scan. 32 chunks of 32 timesteps. Lane owns channel d,
// 16 states in registers. P/S/SIn layout: [c][n][d] (coalesced over d).
// ---------------------------------------------------------------------------
__global__ __launch_bounds__(64) void scan_p1(
    const float* __restrict__ delta, const float* __restrict__ xi_f,
    const float* __restrict__ Bm, const float* __restrict__ A_log,
    float* __restrict__ P, float* __restrict__ S) {
  int d = blockIdx.x * 64 + threadIdx.x;
  int c = blockIdx.y;
  float a[16], p[16], s[16];
  #pragma unroll
  for (int n = 0; n < 16; ++n) {
    a[n] = -__expf(A_log[d * 16 + n]);
    p[n] = 1.f; s[n] = 0.f;
  }
  for (int t = 0; t < 32; ++t) {
    int l = c * 32 + t;
    float dl = delta[(size_t)l * 2048 + d];
    float u  = xi_f[(size_t)l * 2048 + d];
    float du = dl * u;
    float bv[16];
    *(float4*)(bv + 0)  = *(const float4*)&Bm[l * 16 + 0];
    *(float4*)(bv + 4)  = *(const float4*)&Bm[l * 16 + 4];
    *(float4*)(bv + 8)  = *(const float4*)&Bm[l * 16 + 8];
    *(float4*)(bv + 12) = *(const float4*)&Bm[l * 16 + 12];
    #pragma unroll
    for (int n = 0; n < 16; ++n) {
      float dA = __expf(dl * a[n]);
      s[n] = fmaf(dA, s[n], du * bv[n]);
      p[n] *= dA;
    }
  }
  #pragma unroll
  for (int n = 0; n < 16; ++n) {
    P[(size_t)(c * 16 + n) * 2048 + d] = p[n];
    S[(size_t)(c * 16 + n) * 2048 + d] = s[n];
  }
}

__global__ __launch_bounds__(256) void scan_p2(
    const float* __restrict__ P, const float* __restrict__ S,
    float* __restrict__ SIn) {
  int idx = blockIdx.x * 256 + threadIdx.x;  // 0..32767 = n*2048+d
  float sin_ = 0.f;
  for (int c = 0; c < 32; ++c) {
    SIn[c * 32768 + idx] = sin_;
    sin_ = fmaf(P[c * 32768 + idx], sin_, S[c * 32768 + idx]);
  }
}

__global__ __launch_bounds__(64) void scan_p3(
    const float* __restrict__ delta, const float* __restrict__ xi_f,
    const float* __restrict__ Bm, const float* __restrict__ Cm,
    const float* __restrict__ A_log, const float* __restrict__ Dv,
    const float* __restrict__ SIn, const float* __restrict__ xz,
    unsigned short* __restrict__ y_b) {
  int d = blockIdx.x * 64 + threadIdx.x;
  int c = blockIdx.y;
  float a[16], s[16];
  #pragma unroll
  for (int n = 0; n < 16; ++n) {
    a[n] = -__expf(A_log[d * 16 + n]);
    s[n] = SIn[c * 32768 + n * 2048 + d];
  }
  float Dd = Dv[d];
  for (int t = 0; t < 32; ++t) {
    int l = c * 32 + t;
    float dl = delta[(size_t)l * 2048 + d];
    float u  = xi_f[(size_t)l * 2048 + d];
    float du = dl * u;
    float bv[16], cv[16];
    *(float4*)(bv + 0)  = *(const float4*)&Bm[l * 16 + 0];
    *(float4*)(bv + 4)  = *(const float4*)&Bm[l * 16 + 4];
    *(float4*)(bv + 8)  = *(const float4*)&Bm[l * 16 + 8];
    *(float4*)(bv + 12) = *(const float4*)&Bm[l * 16 + 12];
    *(float4*)(cv + 0)  = *(const float4*)&Cm[l * 16 + 0];
    *(float4*)(cv + 4)  = *(const float4*)&Cm[l * 16 + 4];
    *(float4*)(cv + 8)  = *(const float4*)&Cm[l * 16 + 8];
    *(float4*)(cv + 12) = *(const float4*)&Cm[l * 16 + 12];
    float y = 0.f;
    #pragma unroll
    for (int n = 0; n < 16; ++n) {
      float dA = __expf(dl * a[n]);
      s[n] = fmaf(dA, s[n], du * bv[n]);
      y = fmaf(s[n], cv[n], y);
    }
    y = fmaf(u, Dd, y);
    float zz = xz[(size_t)l * 4096 + 2048 + d];
    float sig = 1.f / (1.f + __expf(-zz));
    y *= zz * sig;  // y * silu(z)
    y_b[(size_t)l * 2048 + d] = f2bf(y);
  }
}

// ---------------------------------------------------------------------------
extern "C" void kernel_launch(void* const* d_in, const int* in_sizes, int n_in,
                              void* d_out, int out_size, void* d_ws, size_t ws_size,
                              hipStream_t stream) {
  const float* x      = (const float*)d_in[0];
  const float* Win    = (const float*)d_in[1];
  const float* convw  = (const float*)d_in[2];
  const float* convb  = (const float*)d_in[3];
  const float* xprojw = (const float*)d_in[4];
  const float* dtw    = (const float*)d_in[5];
  const float* dtb    = (const float*)d_in[6];
  const float* Alog   = (const float*)d_in[7];
  const float* Dv     = (const float*)d_in[8];
  const float* Wout   = (const float*)d_in[9];
  float* out = (float*)d_out;

  char* ws = (char*)d_ws;
  size_t off = 0;
  auto alloc = [&](size_t bytes) -> void* {
    void* p = ws + off;
    off = (off + bytes + 255) & ~(size_t)255;
    return p;
  };
  unsigned short* x_bf    = (unsigned short*)alloc((size_t)1024 * 1024 * 2);
  unsigned short* Win_bf  = (unsigned short*)alloc((size_t)4096 * 1024 * 2);
  unsigned short* Wout_bf = (unsigned short*)alloc((size_t)1024 * 2048 * 2);
  unsigned short* xw_bf   = (unsigned short*)alloc((size_t)96 * 2048 * 2);
  unsigned short* dtw_bf  = (unsigned short*)alloc((size_t)2048 * 64 * 2);
  float* xz               = (float*)alloc((size_t)1024 * 4096 * 4);
  float* xi_f             = (float*)alloc((size_t)1024 * 2048 * 4);
  unsigned short* xi_bf   = (unsigned short*)alloc((size_t)1024 * 2048 * 2);
  unsigned short* xd_bf   = (unsigned short*)alloc((size_t)1024 * 64 * 2);
  float* Bm               = (float*)alloc((size_t)1024 * 16 * 4);
  float* Cm               = (float*)alloc((size_t)1024 * 16 * 4);
  float* delta            = (float*)alloc((size_t)1024 * 2048 * 4);
  float* P                = (float*)alloc((size_t)32 * 16 * 2048 * 4);  // 4MB
  float* S                = (float*)alloc((size_t)32 * 16 * 2048 * 4);  // 4MB (contig after P)
  float* SIn              = (float*)alloc((size_t)32 * 16 * 2048 * 4);
  unsigned short* y_bf    = (unsigned short*)alloc((size_t)1024 * 2048 * 2);
  // P and S are dead after scan_p2 -> reused as the 2 split-K partials
  // (they are contiguous: S == P + 1M floats exactly).

  convert_all<<<dim3(512, 5), 256, 0, stream>>>(
      x, x_bf, 1024 * 1024,
      Win, Win_bf, 4096 * 1024,
      Wout, Wout_bf, 1024 * 2048,
      xprojw, xw_bf, 96 * 2048,
      dtw, dtw_bf, 2048 * 64);
  gemm64<1><<<dim3(64, 16), 256, 0, stream>>>(x_bf, Win_bf, xz, 1024, 4096, 1024);
  conv_silu<<<dim3(8, 1024), 256, 0, stream>>>(xz, convw, convb, xi_f, xi_bf);
  xproj<<<dim3(64, 6), 256, 0, stream>>>(xi_bf, xw_bf, xd_bf, Bm, Cm);
  dtproj<<<dim3(64, 128), 64, 0, stream>>>(xd_bf, dtw_bf, dtb, delta);
  scan_p1<<<dim3(32, 32), 64, 0, stream>>>(delta, xi_f, Bm, Alog, P, S);
  scan_p2<<<dim3(128), 256, 0, stream>>>(P, S, SIn);
  scan_p3<<<dim3(32, 32), 64, 0, stream>>>(delta, xi_f, Bm, Cm, Alog, Dv, SIn, xz, y_bf);
  // out_proj with split-K=2: partials into P (dead), then reduce
  gemm64<2><<<dim3(16, 16, 2), 256, 0, stream>>>(y_bf, Wout_bf, P, 1024, 1024, 2048);
  reduce2<<<dim3(1024), 256, 0, stream>>>(P, out, 262144);
}

// Round 3
// 109.556 us; speedup vs baseline: 1.4894x; 1.0766x over previous
//
#include <hip/hip_runtime.h>
#include <hip/hip_bf16.h>
#include <cstdint>
#include <cstddef>

// ---------------------------------------------------------------------------
// Mamba block forward, MI355X (gfx950).  Round 3.
// Changes vs round 2:
//  - xz stored bf16 (gemm_in epilogue casts); conv + z-gate read bf16.
//  - xi kept only in bf16 (scan reads u as bf16); xi_f dropped.
//  - scan p1 unroll x4 / p3 unroll x2 with batched upfront loads.
//  - bijective XCD-chunked block swizzle on both GEMMs (N-slab per XCD).
//  - conv_silu vectorized (short8), 4 rows per block.
// ---------------------------------------------------------------------------

typedef __attribute__((ext_vector_type(4))) float f32x4;
typedef __attribute__((ext_vector_type(8))) short short8;

#define GLOAD_LDS16(g, l)                                                      \
  __builtin_amdgcn_global_load_lds(                                            \
      (const __attribute__((address_space(1))) void*)(g),                      \
      (__attribute__((address_space(3))) void*)(l), 16, 0, 0)

__device__ __forceinline__ unsigned short f2bf(float f) {
  union { float f; unsigned u; } v; v.f = f;
  unsigned u = v.u;
  unsigned r = (u + 0x7FFFu + ((u >> 16) & 1u)) >> 16;  // round-to-nearest-even
  return (unsigned short)r;
}
__device__ __forceinline__ float bf2f(unsigned short u) {
  union { unsigned u; float f; } v; v.u = ((unsigned)u) << 16;
  return v.f;
}

// ---------------------------------------------------------------------------
// fp32 -> bf16 conversion for 5 arrays (blockIdx.y picks the array)
// ---------------------------------------------------------------------------
__global__ __launch_bounds__(256) void convert_all(
    const float* __restrict__ a0, unsigned short* __restrict__ o0, int n0,
    const float* __restrict__ a1, unsigned short* __restrict__ o1, int n1,
    const float* __restrict__ a2, unsigned short* __restrict__ o2, int n2,
    const float* __restrict__ a3, unsigned short* __restrict__ o3, int n3,
    const float* __restrict__ a4, unsigned short* __restrict__ o4, int n4) {
  const float* a; unsigned short* o; int n;
  switch (blockIdx.y) {
    case 0: a = a0; o = o0; n = n0; break;
    case 1: a = a1; o = o1; n = n1; break;
    case 2: a = a2; o = o2; n = n2; break;
    case 3: a = a3; o = o3; n = n3; break;
    default: a = a4; o = o4; n = n4; break;
  }
  int n4c = n >> 2;
  int stride = gridDim.x * blockDim.x;
  for (int i = blockIdx.x * blockDim.x + threadIdx.x; i < n4c; i += stride) {
    float4 v = ((const float4*)a)[i];
    uint2 p;
    p.x = (unsigned)f2bf(v.x) | ((unsigned)f2bf(v.y) << 16);
    p.y = (unsigned)f2bf(v.z) | ((unsigned)f2bf(v.w) << 16);
    ((uint2*)o)[i] = p;
  }
}

// ---------------------------------------------------------------------------
// 64x64-tile bf16 GEMM, C = A @ B^T.  4 waves, 2x2 frags each, BK=64,
// double-buffered LDS, global_load_lds 16B, XOR k-slot swizzle (both sides).
// XCD-chunked bijective block swizzle: XCD k owns N-slab [k*nx/8,(k+1)*nx/8).
// OBF: write C as bf16.  SPLITK>1: blockIdx.z picks K-slice, partials at
// C + z*M*N (fp32 only).
// ---------------------------------------------------------------------------
template <int SPLITK, int OBF>
__global__ __launch_bounds__(256) void gemm64(
    const unsigned short* __restrict__ A, const unsigned short* __restrict__ B,
    void* __restrict__ Cv, int M, int N, int K) {
  __shared__ unsigned short lds[2][2][64 * 64];  // 32KB
  const int tid  = threadIdx.x;
  const int lane = tid & 63;
  const int w    = tid >> 6;

  // bijective XCD-chunked swizzle (requires gridDim.x % 8 == 0)
  const int nx = gridDim.x, ny = gridDim.y;
  int l = (blockIdx.z * ny + blockIdx.y) * nx + blockIdx.x;
  int xcd = l & 7, idx = l >> 3;
  int by = idx % ny;
  int r_ = idx / ny;
  int slab = nx >> 3;
  int bx = xcd * slab + (r_ % slab);
  int bz = r_ / slab;

  const int mBase = by * 64;
  const int nBase = bx * 64;
  const int kLen  = K / SPLITK;
  const int kBase = (SPLITK > 1) ? bz * kLen : 0;
  const int wr = (w >> 1) * 32;
  const int wc = (w & 1) * 32;
  const int wchunk = tid & 192;

  f32x4 acc[2][2];
  #pragma unroll
  for (int m = 0; m < 2; ++m)
    #pragma unroll
    for (int n = 0; n < 2; ++n)
      acc[m][n] = (f32x4){0.f, 0.f, 0.f, 0.f};

  auto stage = [&](int b, int k0) {
    #pragma unroll
    for (int j = 0; j < 2; ++j) {
      int chunk = tid + j * 256;
      int row = chunk >> 3;
      int t = chunk & 7;
      int col = (t ^ (row & 7)) * 8;   // inverse swizzle on global source
      GLOAD_LDS16(&A[(size_t)(mBase + row) * K + k0 + col],
                  &lds[b][0][(size_t)(wchunk + j * 256) * 8]);
      GLOAD_LDS16(&B[(size_t)(nBase + row) * K + k0 + col],
                  &lds[b][1][(size_t)(wchunk + j * 256) * 8]);
    }
  };

  const int kIters = kLen / 64;
  stage(0, kBase);
  __syncthreads();
  int buf = 0;
  for (int it = 0; it < kIters; ++it) {
    if (it + 1 < kIters) stage(buf ^ 1, kBase + (it + 1) * 64);
    short8 af[2][2], bfr[2][2];
    #pragma unroll
    for (int m = 0; m < 2; ++m)
      #pragma unroll
      for (int kk = 0; kk < 2; ++kk) {
        int row = wr + m * 16 + (lane & 15);
        int s = kk * 4 + (lane >> 4);
        af[m][kk] = *(const short8*)&lds[buf][0][row * 64 + ((s ^ (row & 7)) * 8)];
      }
    #pragma unroll
    for (int n = 0; n < 2; ++n)
      #pragma unroll
      for (int kk = 0; kk < 2; ++kk) {
        int row = wc + n * 16 + (lane & 15);
        int s = kk * 4 + (lane >> 4);
        bfr[n][kk] = *(const short8*)&lds[buf][1][row * 64 + ((s ^ (row & 7)) * 8)];
      }
    #pragma unroll
    for (int kk = 0; kk < 2; ++kk)
      #pragma unroll
      for (int m = 0; m < 2; ++m)
        #pragma unroll
        for (int n = 0; n < 2; ++n)
          acc[m][n] = __builtin_amdgcn_mfma_f32_16x16x32_bf16(
              af[m][kk], bfr[n][kk], acc[m][n], 0, 0, 0);
    __syncthreads();
    buf ^= 1;
  }

  if (OBF) {
    unsigned short* Cb = (unsigned short*)Cv;
    #pragma unroll
    for (int m = 0; m < 2; ++m) {
      int row0 = mBase + wr + m * 16 + (lane >> 4) * 4;
      #pragma unroll
      for (int n = 0; n < 2; ++n) {
        int col = nBase + wc + n * 16 + (lane & 15);
        #pragma unroll
        for (int r = 0; r < 4; ++r)
          Cb[(size_t)(row0 + r) * N + col] = f2bf(acc[m][n][r]);
      }
    }
  } else {
    float* Co = (float*)Cv + (SPLITK > 1 ? (size_t)bz * M * N : (size_t)0);
    #pragma unroll
    for (int m = 0; m < 2; ++m) {
      int row0 = mBase + wr + m * 16 + (lane >> 4) * 4;
      #pragma unroll
      for (int n = 0; n < 2; ++n) {
        int col = nBase + wc + n * 16 + (lane & 15);
        #pragma unroll
        for (int r = 0; r < 4; ++r)
          Co[(size_t)(row0 + r) * N + col] = acc[m][n][r];
      }
    }
  }
}

// out = partial0 + partial1 (split-K reduce), vectorized
__global__ __launch_bounds__(256) void reduce2(
    const float* __restrict__ P, float* __restrict__ out, int n4) {
  int i = blockIdx.x * 256 + threadIdx.x;
  if (i < n4) {
    f32x4 a = ((const f32x4*)P)[i];
    f32x4 b = ((const f32x4*)P)[i + n4];
    ((f32x4*)out)[i] = a + b;
  }
}

// ---------------------------------------------------------------------------
// causal depthwise conv (width 4) + silu, bf16 in (xz cols 0..2047) -> bf16 xi
// block: 256 threads, each owns 8 channels; 4 output rows per block.
// ---------------------------------------------------------------------------
__global__ __launch_bounds__(256) void conv_silu(
    const unsigned short* __restrict__ xz_bf, const float* __restrict__ cw,
    const float* __restrict__ cb, unsigned short* __restrict__ xi_b) {
  int d0 = threadIdx.x * 8;
  int l0 = blockIdx.x * 4;
  float wgt[8][4], bias[8];
  #pragma unroll
  for (int j = 0; j < 8; ++j) {
    float4 t = *(const float4*)&cw[(d0 + j) * 4];
    wgt[j][0] = t.x; wgt[j][1] = t.y; wgt[j][2] = t.z; wgt[j][3] = t.w;
  }
  *(float4*)(bias + 0) = *(const float4*)&cb[d0];
  *(float4*)(bias + 4) = *(const float4*)&cb[d0 + 4];

  short8 rows[7];
  #pragma unroll
  for (int r = 0; r < 7; ++r) {
    int ll = l0 - 3 + r;
    if (ll >= 0)
      rows[r] = *(const short8*)&xz_bf[(size_t)ll * 4096 + d0];
    else
      rows[r] = (short8){0, 0, 0, 0, 0, 0, 0, 0};
  }
  #pragma unroll
  for (int q = 0; q < 4; ++q) {
    short8 outv;
    #pragma unroll
    for (int j = 0; j < 8; ++j) {
      float acc = bias[j];
      #pragma unroll
      for (int k = 0; k < 4; ++k)
        acc = fmaf(bf2f((unsigned short)rows[q + k][j]), wgt[j][k], acc);
      float s = acc / (1.f + __expf(-acc));
      outv[j] = (short)f2bf(s);
    }
    *(short8*)&xi_b[(size_t)(l0 + q) * 2048 + d0] = outv;
  }
}

// ---------------------------------------------------------------------------
// x_dbl = xi @ x_proj_w^T  (M=1024, N=96, K=2048).  4 waves split K, LDS
// reduce.  cols 0..63 -> delta_raw (bf16), 64..79 -> Bm, 80..95 -> Cm (fp32)
// ---------------------------------------------------------------------------
__global__ __launch_bounds__(256) void xproj(
    const unsigned short* __restrict__ xi_b, const unsigned short* __restrict__ xw_b,
    unsigned short* __restrict__ xd_b, float* __restrict__ Bm, float* __restrict__ Cm) {
  __shared__ f32x4 red[4][64];
  int tid = threadIdx.x, lane = tid & 63, w = tid >> 6;
  int mt = blockIdx.x, nt = blockIdx.y;
  int arow = mt * 16 + (lane & 15);
  int brow = nt * 16 + (lane & 15);
  int kg = (lane >> 4) * 8;
  f32x4 acc = (f32x4){0.f, 0.f, 0.f, 0.f};
  for (int k0 = w * 512; k0 < (w + 1) * 512; k0 += 32) {
    short8 a = *(const short8*)&xi_b[(size_t)arow * 2048 + k0 + kg];
    short8 b = *(const short8*)&xw_b[(size_t)brow * 2048 + k0 + kg];
    acc = __builtin_amdgcn_mfma_f32_16x16x32_bf16(a, b, acc, 0, 0, 0);
  }
  red[w][lane] = acc;
  __syncthreads();
  if (w == 0) {
    acc = red[0][lane];
    acc += red[1][lane];
    acc += red[2][lane];
    acc += red[3][lane];
    int ocol = nt * 16 + (lane & 15);
    #pragma unroll
    for (int r = 0; r < 4; ++r) {
      int row = mt * 16 + (lane >> 4) * 4 + r;
      float v = acc[r];
      if (ocol < 64)      xd_b[row * 64 + ocol] = f2bf(v);
      else if (ocol < 80) Bm[row * 16 + (ocol - 64)] = v;
      else                Cm[row * 16 + (ocol - 80)] = v;
    }
  }
}

// ---------------------------------------------------------------------------
// delta = softplus(delta_raw @ dt_proj_w^T + dt_proj_b)  (M=1024,N=2048,K=64)
// ---------------------------------------------------------------------------
__global__ __launch_bounds__(64) void dtproj(
    const unsigned short* __restrict__ xd_b, const unsigned short* __restrict__ dtw_b,
    const float* __restrict__ dtb, float* __restrict__ delta) {
  int lane = threadIdx.x;
  int mt = blockIdx.x, nt = blockIdx.y;
  int arow = mt * 16 + (lane & 15);
  int brow = nt * 16 + (lane & 15);
  int kg = (lane >> 4) * 8;
  f32x4 acc = (f32x4){0.f, 0.f, 0.f, 0.f};
  #pragma unroll
  for (int k0 = 0; k0 < 64; k0 += 32) {
    short8 a = *(const short8*)&xd_b[arow * 64 + k0 + kg];
    short8 b = *(const short8*)&dtw_b[brow * 64 + k0 + kg];
    acc = __builtin_amdgcn_mfma_f32_16x16x32_bf16(a, b, acc, 0, 0, 0);
  }
  int ocol = nt * 16 + (lane & 15);
  float bias = dtb[ocol];
  #pragma unroll
  for (int r = 0; r < 4; ++r) {
    int row = mt * 16 + (lane >> 4) * 4 + r;
    float v = acc[r] + bias;
    float sp = (v > 20.f) ? v : log1pf(__expf(v));  // softplus
    delta[(size_t)row * 2048 + ocol] = sp;
  }
}

// ---------------------------------------------------------------------------
// Chunked selective scan. 32 chunks of 32 timesteps. Lane owns channel d,
// 16 states in registers. P/S/SIn layout: [c][n][d].
// p1: unroll x4 with batched loads.
// ---------------------------------------------------------------------------
__global__ __launch_bounds__(64) void scan_p1(
    const float* __restrict__ delta, const unsigned short* __restrict__ xi_b,
    const float* __restrict__ Bm, const float* __restrict__ A_log,
    float* __restrict__ P, float* __restrict__ S) {
  int d = blockIdx.x * 64 + threadIdx.x;
  int c = blockIdx.y;
  float a[16], p[16], s[16];
  #pragma unroll
  for (int n = 0; n < 16; ++n) {
    a[n] = -__expf(A_log[d * 16 + n]);
    p[n] = 1.f; s[n] = 0.f;
  }
  for (int tb = 0; tb < 8; ++tb) {
    int l0 = c * 32 + tb * 4;
    float dl[4], uu[4], bv[4][16];
    #pragma unroll
    for (int q = 0; q < 4; ++q) {
      dl[q] = delta[(size_t)(l0 + q) * 2048 + d];
      uu[q] = bf2f(xi_b[(size_t)(l0 + q) * 2048 + d]);
      *(float4*)(bv[q] + 0)  = *(const float4*)&Bm[(l0 + q) * 16 + 0];
      *(float4*)(bv[q] + 4)  = *(const float4*)&Bm[(l0 + q) * 16 + 4];
      *(float4*)(bv[q] + 8)  = *(const float4*)&Bm[(l0 + q) * 16 + 8];
      *(float4*)(bv[q] + 12) = *(const float4*)&Bm[(l0 + q) * 16 + 12];
    }
    #pragma unroll
    for (int q = 0; q < 4; ++q) {
      float du = dl[q] * uu[q];
      #pragma unroll
      for (int n = 0; n < 16; ++n) {
        float dA = __expf(dl[q] * a[n]);
        s[n] = fmaf(dA, s[n], du * bv[q][n]);
        p[n] *= dA;
      }
    }
  }
  #pragma unroll
  for (int n = 0; n < 16; ++n) {
    P[(size_t)(c * 16 + n) * 2048 + d] = p[n];
    S[(size_t)(c * 16 + n) * 2048 + d] = s[n];
  }
}

__global__ __launch_bounds__(256) void scan_p2(
    const float* __restrict__ P, const float* __restrict__ S,
    float* __restrict__ SIn) {
  int idx = blockIdx.x * 256 + threadIdx.x;  // 0..32767 = n*2048+d
  float sin_ = 0.f;
  #pragma unroll 8
  for (int c = 0; c < 32; ++c) {
    SIn[c * 32768 + idx] = sin_;
    sin_ = fmaf(P[c * 32768 + idx], sin_, S[c * 32768 + idx]);
  }
}

__global__ __launch_bounds__(64) void scan_p3(
    const float* __restrict__ delta, const unsigned short* __restrict__ xi_b,
    const float* __restrict__ Bm, const float* __restrict__ Cm,
    const float* __restrict__ A_log, const float* __restrict__ Dv,
    const float* __restrict__ SIn, const unsigned short* __restrict__ xz_bf,
    unsigned short* __restrict__ y_b) {
  int d = blockIdx.x * 64 + threadIdx.x;
  int c = blockIdx.y;
  float a[16], s[16];
  #pragma unroll
  for (int n = 0; n < 16; ++n) {
    a[n] = -__expf(A_log[d * 16 + n]);
    s[n] = SIn[c * 32768 + n * 2048 + d];
  }
  float Dd = Dv[d];
  for (int tb = 0; tb < 16; ++tb) {
    int l0 = c * 32 + tb * 2;
    float dl[2], uu[2], zz[2], bv[2][16], cv[2][16];
    #pragma unroll
    for (int q = 0; q < 2; ++q) {
      int l = l0 + q;
      dl[q] = delta[(size_t)l * 2048 + d];
      uu[q] = bf2f(xi_b[(size_t)l * 2048 + d]);
      zz[q] = bf2f(xz_bf[(size_t)l * 4096 + 2048 + d]);
      *(float4*)(bv[q] + 0)  = *(const float4*)&Bm[l * 16 + 0];
      *(float4*)(bv[q] + 4)  = *(const float4*)&Bm[l * 16 + 4];
      *(float4*)(bv[q] + 8)  = *(const float4*)&Bm[l * 16 + 8];
      *(float4*)(bv[q] + 12) = *(const float4*)&Bm[l * 16 + 12];
      *(float4*)(cv[q] + 0)  = *(const float4*)&Cm[l * 16 + 0];
      *(float4*)(cv[q] + 4)  = *(const float4*)&Cm[l * 16 + 4];
      *(float4*)(cv[q] + 8)  = *(const float4*)&Cm[l * 16 + 8];
      *(float4*)(cv[q] + 12) = *(const float4*)&Cm[l * 16 + 12];
    }
    #pragma unroll
    for (int q = 0; q < 2; ++q) {
      float du = dl[q] * uu[q];
      float y = 0.f;
      #pragma unroll
      for (int n = 0; n < 16; ++n) {
        float dA = __expf(dl[q] * a[n]);
        s[n] = fmaf(dA, s[n], du * bv[q][n]);
        y = fmaf(s[n], cv[q][n], y);
      }
      y = fmaf(uu[q], Dd, y);
      float sig = 1.f / (1.f + __expf(-zz[q]));
      y *= zz[q] * sig;
      y_b[(size_t)(l0 + q) * 2048 + d] = f2bf(y);
    }
  }
}

// ---------------------------------------------------------------------------
extern "C" void kernel_launch(void* const* d_in, const int* in_sizes, int n_in,
                              void* d_out, int out_size, void* d_ws, size_t ws_size,
                              hipStream_t stream) {
  const float* x      = (const float*)d_in[0];
  const float* Win    = (const float*)d_in[1];
  const float* convw  = (const float*)d_in[2];
  const float* convb  = (const float*)d_in[3];
  const float* xprojw = (const float*)d_in[4];
  const float* dtw    = (const float*)d_in[5];
  const float* dtb    = (const float*)d_in[6];
  const float* Alog   = (const float*)d_in[7];
  const float* Dv     = (const float*)d_in[8];
  const float* Wout   = (const float*)d_in[9];
  float* out = (float*)d_out;

  char* ws = (char*)d_ws;
  size_t off = 0;
  auto alloc = [&](size_t bytes) -> void* {
    void* p = ws + off;
    off = (off + bytes + 255) & ~(size_t)255;
    return p;
  };
  unsigned short* x_bf    = (unsigned short*)alloc((size_t)1024 * 1024 * 2);
  unsigned short* Win_bf  = (unsigned short*)alloc((size_t)4096 * 1024 * 2);
  unsigned short* Wout_bf = (unsigned short*)alloc((size_t)1024 * 2048 * 2);
  unsigned short* xw_bf   = (unsigned short*)alloc((size_t)96 * 2048 * 2);
  unsigned short* dtw_bf  = (unsigned short*)alloc((size_t)2048 * 64 * 2);
  unsigned short* xz_bf   = (unsigned short*)alloc((size_t)1024 * 4096 * 2);
  unsigned short* xi_bf   = (unsigned short*)alloc((size_t)1024 * 2048 * 2);
  unsigned short* xd_bf   = (unsigned short*)alloc((size_t)1024 * 64 * 2);
  float* Bm               = (float*)alloc((size_t)1024 * 16 * 4);
  float* Cm               = (float*)alloc((size_t)1024 * 16 * 4);
  float* delta            = (float*)alloc((size_t)1024 * 2048 * 4);
  float* P                = (float*)alloc((size_t)32 * 16 * 2048 * 4);  // 4MB
  float* S                = (float*)alloc((size_t)32 * 16 * 2048 * 4);  // 4MB, contiguous after P
  float* SIn              = (float*)alloc((size_t)32 * 16 * 2048 * 4);
  unsigned short* y_bf    = (unsigned short*)alloc((size_t)1024 * 2048 * 2);
  // P,S dead after scan_p2 -> reused as split-K partials (contiguous 8MB).

  convert_all<<<dim3(512, 5), 256, 0, stream>>>(
      x, x_bf, 1024 * 1024,
      Win, Win_bf, 4096 * 1024,
      Wout, Wout_bf, 1024 * 2048,
      xprojw, xw_bf, 96 * 2048,
      dtw, dtw_bf, 2048 * 64);
  gemm64<1, 1><<<dim3(64, 16), 256, 0, stream>>>(x_bf, Win_bf, xz_bf, 1024, 4096, 1024);
  conv_silu<<<dim3(256), 256, 0, stream>>>(xz_bf, convw, convb, xi_bf);
  xproj<<<dim3(64, 6), 256, 0, stream>>>(xi_bf, xw_bf, xd_bf, Bm, Cm);
  dtproj<<<dim3(64, 128), 64, 0, stream>>>(xd_bf, dtw_bf, dtb, delta);
  scan_p1<<<dim3(32, 32), 64, 0, stream>>>(delta, xi_bf, Bm, Alog, P, S);
  scan_p2<<<dim3(128), 256, 0, stream>>>(P, S, SIn);
  scan_p3<<<dim3(32, 32), 64, 0, stream>>>(delta, xi_bf, Bm, Cm, Alog, Dv, SIn, xz_bf, y_bf);
  gemm64<2, 0><<<dim3(16, 16, 2), 256, 0, stream>>>(y_bf, Wout_bf, P, 1024, 1024, 2048);
  reduce2<<<dim3(1024), 256, 0, stream>>>(P, out, 262144);
}